// Round 1
// baseline (24363.329 us; speedup 1.0000x reference)
//
#include <hip/hip_runtime.h>
#include <math.h>

// ---------------------------------------------------------------------------
// Kool attention-model greedy decode, B=1024, N=128, D=256, H=8, DH=32.
// Round-1 design notes (theory in commit message):
//  * E-resident attention: compat = (q2 @ WkT-strips) . E ; heads = (attn@E) @ Wv-strips
//    -> only E (134MB) streams per step; fits 256MB LLC. No Kh/Vh/logitK tensors.
//  * Weight folds: M1 = Wo@Wc, M2 = Wo@Wlk^T  => glimpse never materialized.
//  * Visited-compaction: softmax/argmax over unvisited list only (exactly equal in fp32:
//    expf(-1e9 - m) == 0; ascending list preserves argmax first-index tie-break).
//  * 4 kernels per step: pre (ctx@Ws + MLP + qk), flash (online-softmax attn@E),
//    post (heads + M1/M2), select (logits/tanh/argmax/update). 518 graph nodes total.
// ---------------------------------------------------------------------------

#define BB 1024
#define NN 128
#define DD 256
#define HH 8
#define NEGV -1e9f

// ---------------- init ----------------
__global__ void k_zero(unsigned* vis, int* first, int* prev, float* ll, float* cost,
                       float* fxy, float* pxy) {
  int i = blockIdx.x * 256 + threadIdx.x;
  if (i < BB * NN) vis[i] = 0u;
  if (i < BB) { first[i] = 0; prev[i] = 0; ll[i] = 0.f; cost[i] = 0.f; }
  if (i < 2 * BB) { fxy[i] = 0.f; pxy[i] = 0.f; }
}

// glimpse0 = mean_n E
__global__ void k_mean(const float* __restrict__ E, float* __restrict__ g0) {
  int b = blockIdx.x, t = threadIdx.x;
  const float* e = E + (size_t)b * NN * DD + t;
  float s = 0.f;
#pragma unroll 8
  for (int n = 0; n < NN; ++n) s += e[n * DD];
  g0[b * DD + t] = s * (1.f / 128.f);
}

// WkT[o][i] = Wk[i][o]  (256x256)
__global__ void k_transpose(const float* __restrict__ A, float* __restrict__ AT) {
  __shared__ float tile[32][33];
  int bi = blockIdx.x & 7, bo = blockIdx.x >> 3;
  int tx = threadIdx.x & 31, ty = threadIdx.x >> 5;
  for (int j = 0; j < 32; j += 8)
    tile[ty + j][tx] = A[(size_t)(bi * 32 + ty + j) * DD + bo * 32 + tx];
  __syncthreads();
  for (int j = 0; j < 32; j += 8)
    AT[(size_t)(bo * 32 + ty + j) * DD + bi * 32 + tx] = tile[tx][ty + j];
}

// generic C[M,N] = A[M,K] @ B[K,N]   (transB: C[m][n] = sum_k A[m,k]*B[n,k])
__global__ __launch_bounds__(256) void k_gemm(const float* __restrict__ A,
                                              const float* __restrict__ Bm,
                                              float* __restrict__ C,
                                              int M, int Nn, int K, int transB) {
  __shared__ float As[32][33], Bs[32][33];
  int tn = blockIdx.x, tm = blockIdx.y;
  int t = threadIdx.x;
  int c = t & 31, r4 = t >> 5;
  float acc[4] = {0.f, 0.f, 0.f, 0.f};
  for (int k0 = 0; k0 < K; k0 += 32) {
#pragma unroll
    for (int i = 0; i < 4; ++i) {
      int li = t + i * 256; int ar = li >> 5, ac = li & 31;
      As[ar][ac] = A[(size_t)(tm * 32 + ar) * K + k0 + ac];
    }
    if (!transB) {
#pragma unroll
      for (int i = 0; i < 4; ++i) {
        int li = t + i * 256; int kk = li >> 5, cc = li & 31;
        Bs[kk][cc] = Bm[(size_t)(k0 + kk) * Nn + tn * 32 + cc];
      }
    } else {
#pragma unroll
      for (int i = 0; i < 4; ++i) {
        int li = t + i * 256; int cc = li >> 5, kk = li & 31;
        Bs[kk][cc] = Bm[(size_t)(tn * 32 + cc) * K + k0 + kk];
      }
    }
    __syncthreads();
#pragma unroll
    for (int kk = 0; kk < 32; ++kk) {
      float bv = Bs[kk][c];
#pragma unroll
      for (int i = 0; i < 4; ++i) acc[i] += As[r4 + i * 8][kk] * bv;
    }
    __syncthreads();
  }
#pragma unroll
  for (int i = 0; i < 4; ++i)
    C[(size_t)(tm * 32 + r4 + i * 8) * Nn + tn * 32 + c] = acc[i];
}

// ---------------- per-step kernels ----------------

// q = q_lin + ctx@Ws ; h = relu(q@W1+b1) ; q2 = q + h@W2 + b2 ; qk = q2 @ WkT strips
// 4 batch rows per block, 256 threads (group g = row, cols = lane*4 + j).
__global__ __launch_bounds__(256) void k_pre(int step, const float* __restrict__ E,
    const float* __restrict__ Ws, const float* __restrict__ W1, const float* __restrict__ b1,
    const float* __restrict__ W2, const float* __restrict__ b2, const float* __restrict__ WkT,
    const float* __restrict__ Wph, const float* __restrict__ q_lin,
    const int* __restrict__ first, const int* __restrict__ prev, float* __restrict__ qk) {
  __shared__ float ctx[4][512];
  __shared__ float qbuf[4][256];
  __shared__ float hbuf[4][256];
  int t = threadIdx.x, g = t >> 6, lane = t & 63;
  int b = blockIdx.x * 4 + g;
  int c0 = lane * 4;

  if (step == 0) {
#pragma unroll
    for (int j = 0; j < 8; ++j) ctx[g][lane + 64 * j] = Wph[lane + 64 * j];
  } else {
    int f = first[b], p = prev[b];
    float4 vf = *(const float4*)(E + (size_t)b * NN * DD + (size_t)f * DD + c0);
    float4 vp = *(const float4*)(E + (size_t)b * NN * DD + (size_t)p * DD + c0);
    *(float4*)&ctx[g][c0] = vf;
    *(float4*)&ctx[g][256 + c0] = vp;
  }
  __syncthreads();

  // q = q_lin + ctx @ Ws
  float4 qv = *(const float4*)(q_lin + (size_t)b * DD + c0);
#pragma unroll 4
  for (int k = 0; k < 512; ++k) {
    float cv = ctx[g][k];
    float4 w = *(const float4*)(Ws + (size_t)k * DD + c0);
    qv.x += cv * w.x; qv.y += cv * w.y; qv.z += cv * w.z; qv.w += cv * w.w;
  }
  *(float4*)&qbuf[g][c0] = qv;
  __syncthreads();

  // h = relu(q@W1 + b1)
  float4 hv = *(const float4*)(b1 + c0);
#pragma unroll 4
  for (int k = 0; k < 256; ++k) {
    float qq = qbuf[g][k];
    float4 w = *(const float4*)(W1 + (size_t)k * DD + c0);
    hv.x += qq * w.x; hv.y += qq * w.y; hv.z += qq * w.z; hv.w += qq * w.w;
  }
  hv.x = fmaxf(hv.x, 0.f); hv.y = fmaxf(hv.y, 0.f);
  hv.z = fmaxf(hv.z, 0.f); hv.w = fmaxf(hv.w, 0.f);
  *(float4*)&hbuf[g][c0] = hv;
  __syncthreads();

  // q2 = q + h@W2 + b2
  float4 bb = *(const float4*)(b2 + c0);
  float4 q2 = make_float4(qv.x + bb.x, qv.y + bb.y, qv.z + bb.z, qv.w + bb.w);
#pragma unroll 4
  for (int k = 0; k < 256; ++k) {
    float hh = hbuf[g][k];
    float4 w = *(const float4*)(W2 + (size_t)k * DD + c0);
    q2.x += hh * w.x; q2.y += hh * w.y; q2.z += hh * w.z; q2.w += hh * w.w;
  }
  *(float4*)&qbuf[g][c0] = q2;   // safe: nobody reads qbuf between barriers
  __syncthreads();

  // qk[b][h][din] = sum_dh q2[h*32+dh] * WkT[h*32+dh][din]
#pragma unroll
  for (int h = 0; h < HH; ++h) {
    float4 a = {0.f, 0.f, 0.f, 0.f};
#pragma unroll 4
    for (int dh = 0; dh < 32; ++dh) {
      float qq = qbuf[g][h * 32 + dh];
      float4 w = *(const float4*)(WkT + (size_t)(h * 32 + dh) * DD + c0);
      a.x += qq * w.x; a.y += qq * w.y; a.z += qq * w.z; a.w += qq * w.w;
    }
    *(float4*)(qk + (size_t)b * 2048 + h * 256 + c0) = a;
  }
}

// Online-softmax attention over unvisited nodes. One block per batch row.
// Outputs hEn[b][h][din] = (softmax(compat) @ E)[h][din]  (normalized).
__global__ __launch_bounds__(256) void k_flash(const float* __restrict__ E,
    const float* __restrict__ qk, const unsigned* __restrict__ vis,
    float* __restrict__ hEn) {
  __shared__ float Et[16 * 260];
  __shared__ float qkl[2048];
  __shared__ float pl[HH * 16];
  __shared__ int   lst[128];
  __shared__ int   sc[128];
  __shared__ float m_s[HH], l_s[HH], al_s[HH];
  __shared__ int   cnt_s;

  int b = blockIdx.x, t = threadIdx.x;

  // load qk row
  {
    const float4* src = (const float4*)(qk + (size_t)b * 2048);
    float4 v0 = src[t * 2], v1 = src[t * 2 + 1];
    ((float4*)qkl)[t * 2] = v0; ((float4*)qkl)[t * 2 + 1] = v1;
  }
  if (t < HH) { m_s[t] = -INFINITY; l_s[t] = 0.f; }

  // compact unvisited list (ascending) via inclusive scan
  int flag = 0;
  if (t < 128) { flag = (vis[b * NN + t] == 0u) ? 1 : 0; sc[t] = flag; }
  __syncthreads();
#pragma unroll
  for (int off = 1; off < 128; off <<= 1) {
    int v = 0;
    if (t < 128 && t >= off) v = sc[t - off];
    __syncthreads();
    if (t < 128) sc[t] += v;
    __syncthreads();
  }
  if (t < 128 && flag) lst[sc[t] - 1] = t;
  if (t == 0) cnt_s = sc[127];
  __syncthreads();
  int cnt = cnt_s;
  int ntiles = (cnt + 15) >> 4;

  int h = t >> 5, sub = t & 31, nn = sub >> 1, half = sub & 1;
  float hE[HH];
#pragma unroll
  for (int i = 0; i < HH; ++i) hE[i] = 0.f;

  for (int tile = 0; tile < ntiles; ++tile) {
    int nt = cnt - tile * 16; if (nt > 16) nt = 16;
    // stage gathered rows: 16 threads per row, 16 floats each
    {
      int r = t >> 4, chunk = t & 15;
      if (r < nt) {
        int row = lst[tile * 16 + r];
        const float4* src = (const float4*)(E + (size_t)b * NN * DD + (size_t)row * DD + chunk * 16);
        float4 a = src[0], bq = src[1], cq = src[2], dq = src[3];
        float4* dst = (float4*)&Et[r * 260 + chunk * 16];
        dst[0] = a; dst[1] = bq; dst[2] = cq; dst[3] = dq;
      }
    }
    __syncthreads();

    // compat for (h, nn) over din-half
    float acc = 0.f;
    {
      const float4* qp = (const float4*)&qkl[h * 256 + half * 128];
      const float4* ep = (const float4*)&Et[nn * 260 + half * 128];
#pragma unroll 8
      for (int ii = 0; ii < 32; ++ii) {
        float4 qv = qp[ii], ev = ep[ii];
        acc += qv.x * ev.x + qv.y * ev.y + qv.z * ev.z + qv.w * ev.w;
      }
    }
    acc += __shfl_xor(acc, 1);
    acc *= 0.17677669529663687f;   // 1/sqrt(32)

    float tmax = (nn < nt) ? acc : -INFINITY;
    tmax = fmaxf(tmax, __shfl_xor(tmax, 2));
    tmax = fmaxf(tmax, __shfl_xor(tmax, 4));
    tmax = fmaxf(tmax, __shfl_xor(tmax, 8));
    tmax = fmaxf(tmax, __shfl_xor(tmax, 16));

    float mold = m_s[h];
    float newm = fmaxf(mold, tmax);
    float alpha = expf(mold - newm);
    float p = (nn < nt) ? expf(acc - newm) : 0.f;
    float psum = (half == 0) ? p : 0.f;
    psum += __shfl_xor(psum, 1);
    psum += __shfl_xor(psum, 2);
    psum += __shfl_xor(psum, 4);
    psum += __shfl_xor(psum, 8);
    psum += __shfl_xor(psum, 16);

    if (half == 0 && nn < nt) pl[h * 16 + nn] = p;
    if (sub == 0) { m_s[h] = newm; l_s[h] = l_s[h] * alpha + psum; al_s[h] = alpha; }
    __syncthreads();

    // hE update: thread t = din
    {
#pragma unroll
      for (int i = 0; i < HH; ++i) hE[i] *= al_s[i];
      for (int r = 0; r < nt; ++r) {
        float e = Et[r * 260 + t];
#pragma unroll
        for (int i = 0; i < HH; ++i) hE[i] += pl[i * 16 + r] * e;
      }
    }
    __syncthreads();
  }

  // normalize + store
#pragma unroll
  for (int i = 0; i < HH; ++i)
    hEn[(size_t)b * 2048 + i * 256 + t] = hE[i] / l_s[i];
}

// heads = hEn @ Wv strips ; q_lin' = heads@M1 ; gl2 = heads@M2. 4 rows/block.
__global__ __launch_bounds__(256) void k_post(const float* __restrict__ hEn,
    const float* __restrict__ Wv, const float* __restrict__ M1, const float* __restrict__ M2,
    float* __restrict__ q_lin, float* __restrict__ gl2) {
  __shared__ float hEl[4][HH * 260];
  __shared__ float headsl[4][256];
  int t = threadIdx.x, g = t >> 6, lane = t & 63;
  int b = blockIdx.x * 4 + g;
  int c0 = lane * 4;

#pragma unroll
  for (int jj = 0; jj < 8; ++jj) {
    int m = lane * 4 + jj * 256;
    int h = m >> 8, din = m & 255;
    float4 v = *(const float4*)(hEn + (size_t)b * 2048 + m);
    *(float4*)&hEl[g][h * 260 + din] = v;
  }
  __syncthreads();

  int h = c0 >> 5;
  float4 acc = {0.f, 0.f, 0.f, 0.f};
#pragma unroll 4
  for (int din = 0; din < 256; ++din) {
    float v = hEl[g][h * 260 + din];
    float4 w = *(const float4*)(Wv + (size_t)din * DD + c0);
    acc.x += v * w.x; acc.y += v * w.y; acc.z += v * w.z; acc.w += v * w.w;
  }
  *(float4*)&headsl[g][c0] = acc;
  __syncthreads();

  float4 a1 = {0.f, 0.f, 0.f, 0.f}, a2 = {0.f, 0.f, 0.f, 0.f};
#pragma unroll 4
  for (int k = 0; k < 256; ++k) {
    float hd = headsl[g][k];
    float4 w1 = *(const float4*)(M1 + (size_t)k * DD + c0);
    float4 w2 = *(const float4*)(M2 + (size_t)k * DD + c0);
    a1.x += hd * w1.x; a1.y += hd * w1.y; a1.z += hd * w1.z; a1.w += hd * w1.w;
    a2.x += hd * w2.x; a2.y += hd * w2.y; a2.z += hd * w2.z; a2.w += hd * w2.w;
  }
  *(float4*)(q_lin + (size_t)b * DD + c0) = a1;
  *(float4*)(gl2 + (size_t)b * DD + c0) = a2;
}

// logits over unvisited -> 10*tanh(.) -> argmax (first-index ties) -> state update.
__global__ __launch_bounds__(256) void k_select(int step, const float* __restrict__ E,
    const float* __restrict__ coords, const float* __restrict__ gl2,
    unsigned* __restrict__ vis, int* __restrict__ first, int* __restrict__ prev,
    float* __restrict__ fxy, float* __restrict__ pxy,
    float* __restrict__ ll, float* __restrict__ cost, float* __restrict__ out) {
  __shared__ float gl[256];
  __shared__ int   lst[128];
  __shared__ int   sc[128];
  __shared__ float logit_l[128];
  __shared__ float rv[128];
  __shared__ int   ri[128];
  __shared__ float se[128];
  __shared__ int   cnt_s;

  int b = blockIdx.x, t = threadIdx.x;
  gl[t] = gl2[(size_t)b * DD + t];

  int flag = 0;
  if (t < 128) { flag = (vis[b * NN + t] == 0u) ? 1 : 0; sc[t] = flag; }
  __syncthreads();
#pragma unroll
  for (int off = 1; off < 128; off <<= 1) {
    int v = 0;
    if (t < 128 && t >= off) v = sc[t - off];
    __syncthreads();
    if (t < 128) sc[t] += v;
    __syncthreads();
  }
  if (t < 128 && flag) lst[sc[t] - 1] = t;
  if (t == 0) cnt_s = sc[127];
  __syncthreads();
  int cnt = cnt_s;

  // logits: 2 threads per list entry (din halves)
  int idx = t >> 1, half = t & 1;
  float acc = 0.f;
  if (idx < cnt) {
    int n = lst[idx];
    const float4* ep = (const float4*)(E + (size_t)b * NN * DD + (size_t)n * DD + half * 128);
    const float4* gp = (const float4*)&gl[half * 128];
#pragma unroll 8
    for (int ii = 0; ii < 32; ++ii) {
      float4 ev = ep[ii], gv = gp[ii];
      acc += ev.x * gv.x + ev.y * gv.y + ev.z * gv.z + ev.w * gv.w;
    }
  }
  acc += __shfl_xor(acc, 1);
  if (idx < cnt && half == 0) {
    float s = acc * 0.0625f;           // 1/sqrt(256)
    logit_l[idx] = 10.f * tanhf(s);
  }
  __syncthreads();

  if (t < 128) {
    rv[t] = (t < cnt) ? logit_l[t] : -INFINITY;
    ri[t] = t;
  }
  __syncthreads();
#pragma unroll
  for (int off = 64; off >= 1; off >>= 1) {
    if (t < off) {
      float v2 = rv[t + off]; int i2 = ri[t + off];
      if (v2 > rv[t] || (v2 == rv[t] && i2 < ri[t])) { rv[t] = v2; ri[t] = i2; }
    }
    __syncthreads();
  }
  float mx = rv[0];
  if (t < 128) se[t] = (t < cnt) ? expf(logit_l[t] - mx) : 0.f;
  __syncthreads();
#pragma unroll
  for (int off = 64; off >= 1; off >>= 1) {
    if (t < off) se[t] += se[t + off];
    __syncthreads();
  }

  if (t == 0) {
    int sel = lst[ri[0]];
    float logp = -logf(se[0]);
    vis[b * NN + sel] = 1u;
    float cx = coords[(size_t)b * NN * 2 + sel * 2];
    float cy = coords[(size_t)b * NN * 2 + sel * 2 + 1];
    float newll = ll[b] + logp;
    ll[b] = newll;
    float newcost = cost[b];
    if (step == 0) {
      first[b] = sel;
      fxy[b * 2] = cx; fxy[b * 2 + 1] = cy;
    } else {
      float dx = pxy[b * 2] - cx, dy = pxy[b * 2 + 1] - cy;
      newcost += sqrtf(dx * dx + dy * dy);
    }
    prev[b] = sel;
    pxy[b * 2] = cx; pxy[b * 2 + 1] = cy;
    if (step == NN - 1) {
      float dx = cx - fxy[b * 2], dy = cy - fxy[b * 2 + 1];
      newcost += sqrtf(dx * dx + dy * dy);
      out[b] = newcost;
      out[BB + b] = newll;
    }
    cost[b] = newcost;
  }
}

// ---------------------------------------------------------------------------
extern "C" void kernel_launch(void* const* d_in, const int* in_sizes, int n_in,
                              void* d_out, int out_size, void* d_ws, size_t ws_size,
                              hipStream_t stream) {
  const float* coords = (const float*)d_in[0];
  const float* E      = (const float*)d_in[1];
  const float* Wk     = (const float*)d_in[2];
  const float* Wv     = (const float*)d_in[3];
  const float* Wlk    = (const float*)d_in[4];
  const float* Wo     = (const float*)d_in[5];
  const float* Wc     = (const float*)d_in[6];
  const float* Ws     = (const float*)d_in[7];
  const float* Wph    = (const float*)d_in[8];
  const float* W1     = (const float*)d_in[9];
  const float* b1     = (const float*)d_in[10];
  const float* W2     = (const float*)d_in[11];
  const float* b2     = (const float*)d_in[12];
  float* out = (float*)d_out;

  float* w = (float*)d_ws;
  float* qk   = w;                       // B*2048
  float* hEn  = qk + (size_t)BB * 2048;  // B*2048
  float* qlin = hEn + (size_t)BB * 2048; // B*256
  float* gl2  = qlin + (size_t)BB * DD;  // B*256
  float* g0   = gl2 + (size_t)BB * DD;   // B*256
  float* WkT  = g0 + (size_t)BB * DD;    // 256*256
  float* M1   = WkT + DD * DD;           // 256*256
  float* M2   = M1 + DD * DD;            // 256*256
  unsigned* vis = (unsigned*)(M2 + DD * DD);  // B*128 u32
  int* first = (int*)(vis + BB * NN);
  int* prev  = first + BB;
  float* ll  = (float*)(prev + BB);
  float* cost = ll + BB;
  float* fxy = cost + BB;
  float* pxy = fxy + 2 * BB;

  k_zero<<<512, 256, 0, stream>>>(vis, first, prev, ll, cost, fxy, pxy);
  k_mean<<<BB, 256, 0, stream>>>(E, g0);
  k_transpose<<<64, 256, 0, stream>>>(Wk, WkT);
  k_gemm<<<dim3(8, 8), 256, 0, stream>>>(Wo, Wc, M1, 256, 256, 256, 0);
  k_gemm<<<dim3(8, 8), 256, 0, stream>>>(Wo, Wlk, M2, 256, 256, 256, 1);
  k_gemm<<<dim3(8, 32), 256, 0, stream>>>(g0, Wc, qlin, 1024, 256, 256, 0);

  for (int step = 0; step < NN; ++step) {
    k_pre<<<256, 256, 0, stream>>>(step, E, Ws, W1, b1, W2, b2, WkT, Wph,
                                   qlin, first, prev, qk);
    k_flash<<<BB, 256, 0, stream>>>(E, qk, vis, hEn);
    k_post<<<256, 256, 0, stream>>>(hEn, Wv, M1, M2, qlin, gl2);
    k_select<<<BB, 256, 0, stream>>>(step, E, coords, gl2, vis, first, prev,
                                     fxy, pxy, ll, cost, out);
  }
}

// Round 3
// 13421.663 us; speedup vs baseline: 1.8152x; 1.8152x over previous
//
#include <hip/hip_runtime.h>
#include <math.h>

// ---------------------------------------------------------------------------
// Round 3 == round 2 resubmit (round 2 never ran: GPU acquisition timeout).
// Single fused decode kernel (128 steps in-kernel).
//  * Per-b independence => no cross-block sync needed at all.
//  * 256 blocks x 512 thr (8 waves), 4 b's/block, 1 block/CU (LDS ~104KB).
//  * GEMV phases: K-split(8 waves) x b-batch(4): each weight f4 loaded once
//    per block, 16 FMAs (4 b's). Partials in LDS, combine pass.
//  * Flash attn: wave-pair per b; qk fragments in registers (lane=(h,seg));
//    per-lane online softmax state; 8-row tiles; E read direct (L1-hot).
//  * select: logits + argmax/sumexp trees matching round-1 associativity.
// ---------------------------------------------------------------------------

#define BB 1024
#define NN 128
#define DD 256
#define HH 8

__device__ __forceinline__ float4 f4z() { return make_float4(0.f, 0.f, 0.f, 0.f); }
__device__ __forceinline__ float4 f4fma(float4 a, float4 b, float4 c) {
  c.x = fmaf(a.x, b.x, c.x); c.y = fmaf(a.y, b.y, c.y);
  c.z = fmaf(a.z, b.z, c.z); c.w = fmaf(a.w, b.w, c.w); return c;
}
__device__ __forceinline__ float4 svfma(float s, float4 w, float4 c) {
  c.x = fmaf(s, w.x, c.x); c.y = fmaf(s, w.y, c.y);
  c.z = fmaf(s, w.z, c.z); c.w = fmaf(s, w.w, c.w); return c;
}
__device__ __forceinline__ float4 f4scale(float4 a, float s) {
  a.x *= s; a.y *= s; a.z *= s; a.w *= s; return a;
}

#define WAVE_SYNC() do { asm volatile("s_waitcnt lgkmcnt(0)" ::: "memory"); \
                         __builtin_amdgcn_sched_barrier(0); } while (0)

// ---------------- precompute kernels (round-1, proven) ----------------
__global__ void k_mean(const float* __restrict__ E, float* __restrict__ g0) {
  int b = blockIdx.x, t = threadIdx.x;
  const float* e = E + (size_t)b * NN * DD + t;
  float s = 0.f;
#pragma unroll 8
  for (int n = 0; n < NN; ++n) s += e[n * DD];
  g0[b * DD + t] = s * (1.f / 128.f);
}

__global__ void k_transpose(const float* __restrict__ A, float* __restrict__ AT) {
  __shared__ float tile[32][33];
  int bi = blockIdx.x & 7, bo = blockIdx.x >> 3;
  int tx = threadIdx.x & 31, ty = threadIdx.x >> 5;
  for (int j = 0; j < 32; j += 8)
    tile[ty + j][tx] = A[(size_t)(bi * 32 + ty + j) * DD + bo * 32 + tx];
  __syncthreads();
  for (int j = 0; j < 32; j += 8)
    AT[(size_t)(bo * 32 + ty + j) * DD + bi * 32 + tx] = tile[tx][ty + j];
}

__global__ __launch_bounds__(256) void k_gemm(const float* __restrict__ A,
                                              const float* __restrict__ Bm,
                                              float* __restrict__ C,
                                              int M, int Nn, int K, int transB) {
  __shared__ float As[32][33], Bs[32][33];
  int tn = blockIdx.x, tm = blockIdx.y;
  int t = threadIdx.x;
  int c = t & 31, r4 = t >> 5;
  float acc[4] = {0.f, 0.f, 0.f, 0.f};
  for (int k0 = 0; k0 < K; k0 += 32) {
#pragma unroll
    for (int i = 0; i < 4; ++i) {
      int li = t + i * 256; int ar = li >> 5, ac = li & 31;
      As[ar][ac] = A[(size_t)(tm * 32 + ar) * K + k0 + ac];
    }
    if (!transB) {
#pragma unroll
      for (int i = 0; i < 4; ++i) {
        int li = t + i * 256; int kk = li >> 5, cc = li & 31;
        Bs[kk][cc] = Bm[(size_t)(k0 + kk) * Nn + tn * 32 + cc];
      }
    } else {
#pragma unroll
      for (int i = 0; i < 4; ++i) {
        int li = t + i * 256; int cc = li >> 5, kk = li & 31;
        Bs[kk][cc] = Bm[(size_t)(tn * 32 + cc) * K + k0 + kk];
      }
    }
    __syncthreads();
#pragma unroll
    for (int kk = 0; kk < 32; ++kk) {
      float bv = Bs[kk][c];
#pragma unroll
      for (int i = 0; i < 4; ++i) acc[i] += As[r4 + i * 8][kk] * bv;
    }
    __syncthreads();
  }
#pragma unroll
  for (int i = 0; i < 4; ++i)
    C[(size_t)(tm * 32 + r4 + i * 8) * Nn + tn * 32 + c] = acc[i];
}

// ---------------- the fused decode kernel ----------------
__global__ __launch_bounds__(512, 2) void k_decode(
    const float* __restrict__ E, const float* __restrict__ coords,
    const float* __restrict__ Ws, const float* __restrict__ W1,
    const float* __restrict__ b1, const float* __restrict__ W2,
    const float* __restrict__ b2, const float* __restrict__ WkT,
    const float* __restrict__ Wv, const float* __restrict__ M1,
    const float* __restrict__ M2, const float* __restrict__ Wph,
    const float* __restrict__ qlin0, float* __restrict__ out) {
  // [k][bb] interleaved buffers (f4 read gets all 4 b's)
  __shared__ float ctxS[512 * 4];    // 8KB
  __shared__ float qS[256 * 4];      // 4KB
  __shared__ float hS[256 * 4];      // 4KB
  __shared__ float q2S[256 * 4];     // 4KB
  __shared__ float headsS[256 * 4];  // 4KB
  __shared__ float qkS[8320];        // qk [bb][h*260+c] | parts | B-scratch  33KB
  __shared__ float hEnS[8320];       // parts | hEn [(h*260+din)*4+bb]        33KB
  __shared__ float qlinS[4][256];    // persistent glimpse@Wc  4KB
  __shared__ float gl2S[4][256];     // 4KB
  __shared__ float plS[4 * 2 * 8 * 8];
  __shared__ float alS[4 * 2 * 8];
  __shared__ float mlS[4 * 2 * 8 * 2];
  __shared__ int   lstS[4][128];
  __shared__ float logitS[4][128];
  __shared__ unsigned visS[4][4];
  __shared__ int   fpS[4][2];        // first, prev
  __shared__ float stS[4][8];        // ll, cost, fx, fy, px, py

  const int t = threadIdx.x;
  const int w = t >> 6, l = t & 63;
  const int blk = blockIdx.x;
  const int ks = w;                // GEMV k-slice role
  const int c0 = l * 4;            // GEMV col role (f4)
  const int fbb = w >> 1, w2 = w & 1;  // flash roles

  // ---- init ----
  if (t < 256) {
    int bb = t >> 6, cc = (t & 63) * 4;
    *(float4*)&qlinS[bb][cc] =
        *(const float4*)(qlin0 + (size_t)(blk * 4 + bb) * DD + cc);
  }
  if (t < 16) visS[t >> 2][t & 3] = 0u;
  if (t < 4) {
    fpS[t][0] = 0; fpS[t][1] = 0;
#pragma unroll
    for (int j = 0; j < 8; ++j) stS[t][j] = 0.f;
  }
  __syncthreads();

  for (int step = 0; step < NN; ++step) {
    const int cnt = NN - step;

    // ================= PRE =================
    // ctx gather -> ctxS[k][bb]
    if (step == 0) {
      float v = Wph[t];
      *(float4*)&ctxS[t * 4] = make_float4(v, v, v, v);
    } else {
      int bb = t >> 7, i4 = (t & 127) * 4;
      int node = (i4 < 256) ? fpS[bb][0] : fpS[bb][1];
      float4 v = *(const float4*)(E + (size_t)(blk * 4 + bb) * (NN * DD) +
                                  (size_t)node * DD + (i4 & 255));
      ctxS[(i4 + 0) * 4 + bb] = v.x; ctxS[(i4 + 1) * 4 + bb] = v.y;
      ctxS[(i4 + 2) * 4 + bb] = v.z; ctxS[(i4 + 3) * 4 + bb] = v.w;
    }
    __syncthreads();

    // q = qlin + ctx @ Ws   (K=512, slice 64/wave)
    {
      float4 a0 = f4z(), a1 = f4z(), a2 = f4z(), a3 = f4z();
      const float* wp = Ws + (size_t)(ks * 64) * DD + c0;
      const float* cp = ctxS + (ks * 64) * 4;
#pragma unroll 8
      for (int k = 0; k < 64; ++k) {
        float4 wv = *(const float4*)wp; wp += DD;
        float4 cv = *(const float4*)cp; cp += 4;
        a0 = svfma(cv.x, wv, a0); a1 = svfma(cv.y, wv, a1);
        a2 = svfma(cv.z, wv, a2); a3 = svfma(cv.w, wv, a3);
      }
      *(float4*)&hEnS[ks * 1024 + 0 * 256 + c0] = a0;
      *(float4*)&hEnS[ks * 1024 + 1 * 256 + c0] = a1;
      *(float4*)&hEnS[ks * 1024 + 2 * 256 + c0] = a2;
      *(float4*)&hEnS[ks * 1024 + 3 * 256 + c0] = a3;
    }
    __syncthreads();
    {  // q combine
      int bb = t & 3, cb = t >> 2;
#pragma unroll
      for (int it = 0; it < 2; ++it) {
        int c = cb + it * 128;
        float s = qlinS[bb][c];
#pragma unroll
        for (int sl = 0; sl < 8; ++sl) s += hEnS[sl * 1024 + bb * 256 + c];
        qS[c * 4 + bb] = s;
      }
    }
    __syncthreads();

    // h = relu(q @ W1 + b1)  (K=256, slice 32/wave)
    {
      float4 a0 = f4z(), a1 = f4z(), a2 = f4z(), a3 = f4z();
      const float* wp = W1 + (size_t)(ks * 32) * DD + c0;
      const float* qp = qS + (ks * 32) * 4;
#pragma unroll 8
      for (int k = 0; k < 32; ++k) {
        float4 wv = *(const float4*)wp; wp += DD;
        float4 qv = *(const float4*)qp; qp += 4;
        a0 = svfma(qv.x, wv, a0); a1 = svfma(qv.y, wv, a1);
        a2 = svfma(qv.z, wv, a2); a3 = svfma(qv.w, wv, a3);
      }
      *(float4*)&hEnS[ks * 1024 + 0 * 256 + c0] = a0;
      *(float4*)&hEnS[ks * 1024 + 1 * 256 + c0] = a1;
      *(float4*)&hEnS[ks * 1024 + 2 * 256 + c0] = a2;
      *(float4*)&hEnS[ks * 1024 + 3 * 256 + c0] = a3;
    }
    __syncthreads();
    {  // h combine
      int bb = t & 3, cb = t >> 2;
#pragma unroll
      for (int it = 0; it < 2; ++it) {
        int c = cb + it * 128;
        float s = b1[c];
#pragma unroll
        for (int sl = 0; sl < 8; ++sl) s += hEnS[sl * 1024 + bb * 256 + c];
        hS[c * 4 + bb] = fmaxf(s, 0.f);
      }
    }
    __syncthreads();

    // q2 = q + h @ W2 + b2
    {
      float4 a0 = f4z(), a1 = f4z(), a2 = f4z(), a3 = f4z();
      const float* wp = W2 + (size_t)(ks * 32) * DD + c0;
      const float* hp = hS + (ks * 32) * 4;
#pragma unroll 8
      for (int k = 0; k < 32; ++k) {
        float4 wv = *(const float4*)wp; wp += DD;
        float4 hv = *(const float4*)hp; hp += 4;
        a0 = svfma(hv.x, wv, a0); a1 = svfma(hv.y, wv, a1);
        a2 = svfma(hv.z, wv, a2); a3 = svfma(hv.w, wv, a3);
      }
      *(float4*)&hEnS[ks * 1024 + 0 * 256 + c0] = a0;
      *(float4*)&hEnS[ks * 1024 + 1 * 256 + c0] = a1;
      *(float4*)&hEnS[ks * 1024 + 2 * 256 + c0] = a2;
      *(float4*)&hEnS[ks * 1024 + 3 * 256 + c0] = a3;
    }
    __syncthreads();
    {  // q2 combine
      int bb = t & 3, cb = t >> 2;
#pragma unroll
      for (int it = 0; it < 2; ++it) {
        int c = cb + it * 128;
        float s = qS[c * 4 + bb] + b2[c];
#pragma unroll
        for (int sl = 0; sl < 8; ++sl) s += hEnS[sl * 1024 + bb * 256 + c];
        q2S[c * 4 + bb] = s;
      }
    }
    __syncthreads();

    // qk[h] = q2-strip @ WkT-strip   (wave = head)
    {
      const int h = w;
      float4 a0 = f4z(), a1 = f4z(), a2 = f4z(), a3 = f4z();
      const float* wp = WkT + (size_t)(h * 32) * DD + c0;
      const float* qp = q2S + (h * 32) * 4;
#pragma unroll 8
      for (int k = 0; k < 32; ++k) {
        float4 wv = *(const float4*)wp; wp += DD;
        float4 qv = *(const float4*)qp; qp += 4;
        a0 = svfma(qv.x, wv, a0); a1 = svfma(qv.y, wv, a1);
        a2 = svfma(qv.z, wv, a2); a3 = svfma(qv.w, wv, a3);
      }
      *(float4*)&qkS[0 * 2080 + h * 260 + c0] = a0;
      *(float4*)&qkS[1 * 2080 + h * 260 + c0] = a1;
      *(float4*)&qkS[2 * 2080 + h * 260 + c0] = a2;
      *(float4*)&qkS[3 * 2080 + h * 260 + c0] = a3;
    }
    __syncthreads();

    // ================= build unvisited list =================
    {
      int bb = t >> 7, n = t & 127, half = (t >> 6) & 1;
      unsigned wd = visS[bb][n >> 5];
      bool unv = !((wd >> (n & 31)) & 1u);
      unsigned long long m = __ballot(unv);
      int rank = __popcll(m & ((1ull << l) - 1ull));
      int base = half ? (__popc(~visS[bb][0]) + __popc(~visS[bb][1])) : 0;
      if (unv) lstS[bb][base + rank] = n;
    }
    __syncthreads();

    // ================= FLASH (wave-local) =================
    const float* Eb = E + (size_t)(blk * 4 + fbb) * (NN * DD);
    float4 qr[8];
    {
      int h = l >> 3, s8 = l & 7;
#pragma unroll
      for (int j = 0; j < 8; ++j)
        qr[j] = *(float4*)&qkS[fbb * 2080 + h * 260 + s8 * 32 + j * 4];
    }
    __syncthreads();  // qkS scratch reused below; all reg-loads must finish

    float4 hE[8];
#pragma unroll
    for (int i = 0; i < 8; ++i) hE[i] = f4z();
    float m_run = -INFINITY, l_run = 0.f;
    const int nA = (cnt + 1) >> 1;
    const int wstart = w2 ? nA : 0;
    const int wcount = w2 ? (cnt - nA) : nA;
    const int ntl = (wcount + 7) >> 3;
    const int slot = (fbb * 2 + w2) * 8;

    for (int tl = 0; tl < ntl; ++tl) {
      int rem = wcount - tl * 8;
      float pc[8];
      {
        int s8 = l & 7;
#pragma unroll
        for (int r = 0; r < 8; ++r) {
          int idx = wstart + tl * 8 + r;
          int row = lstS[fbb][(r < rem) ? idx : wstart];
          const float* ep = Eb + row * DD + s8 * 32;
          float4 acc = f4z();
#pragma unroll
          for (int j = 0; j < 8; ++j)
            acc = f4fma(*(const float4*)(ep + j * 4), qr[j], acc);
          pc[r] = (acc.x + acc.y) + (acc.z + acc.w);
        }
#pragma unroll
        for (int r = 0; r < 8; ++r) {
          pc[r] += __shfl_xor(pc[r], 1);
          pc[r] += __shfl_xor(pc[r], 2);
          pc[r] += __shfl_xor(pc[r], 4);
          pc[r] = (r < rem) ? pc[r] * 0.17677669529663687f : -INFINITY;
        }
      }
      // online softmax (per-lane; all 8 seg-lanes of a head identical)
      float mt = pc[0];
#pragma unroll
      for (int r = 1; r < 8; ++r) mt = fmaxf(mt, pc[r]);
      float newm = fmaxf(m_run, mt);
      float alpha = expf(m_run - newm);
      float p[8], psum = 0.f;
#pragma unroll
      for (int r = 0; r < 8; ++r) { p[r] = expf(pc[r] - newm); psum += p[r]; }
      l_run = l_run * alpha + psum;
      m_run = newm;
      {
        int h = l >> 3;
        if ((l & 7) == 0) {
#pragma unroll
          for (int r = 0; r < 8; ++r) plS[(slot + r) * 8 + h] = p[r];
          alS[slot + h] = alpha;
        }
      }
      WAVE_SYNC();
      // PV update: lane = din f4
      {
        float al[8];
#pragma unroll
        for (int h = 0; h < 8; ++h) al[h] = alS[slot + h];
#pragma unroll
        for (int h = 0; h < 8; ++h) hE[h] = f4scale(hE[h], al[h]);
        for (int r = 0; r < 8; ++r) {
          int idx = wstart + tl * 8 + r;
          int row = lstS[fbb][(r < rem) ? idx : wstart];
          float4 e4 = *(const float4*)(Eb + row * DD + l * 4);
          float4 p0 = *(float4*)&plS[(slot + r) * 8 + 0];
          float4 p1 = *(float4*)&plS[(slot + r) * 8 + 4];
          hE[0] = svfma(p0.x, e4, hE[0]); hE[1] = svfma(p0.y, e4, hE[1]);
          hE[2] = svfma(p0.z, e4, hE[2]); hE[3] = svfma(p0.w, e4, hE[3]);
          hE[4] = svfma(p1.x, e4, hE[4]); hE[5] = svfma(p1.y, e4, hE[5]);
          hE[6] = svfma(p1.z, e4, hE[6]); hE[7] = svfma(p1.w, e4, hE[7]);
        }
      }
      WAVE_SYNC();  // plS/alS reused next tile
    }
    // publish (m,l); wave B publishes raw hE scratch
    {
      int h = l >> 3;
      if ((l & 7) == 0) {
        mlS[(slot + h) * 2 + 0] = m_run;
        mlS[(slot + h) * 2 + 1] = l_run;
      }
    }
    if (w2 == 1) {
#pragma unroll
      for (int h = 0; h < 8; ++h)
        *(float4*)&qkS[fbb * 2080 + h * 260 + l * 4] = hE[h];
    }
    __syncthreads();
    if (w2 == 0) {  // merge + normalize -> hEnS[(h*260+din)*4+bb]
      int sa = (fbb * 2 + 0) * 8, sb = (fbb * 2 + 1) * 8;
#pragma unroll
      for (int h = 0; h < 8; ++h) {
        float mA = mlS[(sa + h) * 2], lA = mlS[(sa + h) * 2 + 1];
        float mB = mlS[(sb + h) * 2], lB = mlS[(sb + h) * 2 + 1];
        float mm = fmaxf(mA, mB);
        float aA = expf(mA - mm), aB = expf(mB - mm);
        float lt = lA * aA + lB * aB;
        float4 vB = *(float4*)&qkS[fbb * 2080 + h * 260 + l * 4];
        float4 v;
        v.x = (hE[h].x * aA + vB.x * aB) / lt;
        v.y = (hE[h].y * aA + vB.y * aB) / lt;
        v.z = (hE[h].z * aA + vB.z * aB) / lt;
        v.w = (hE[h].w * aA + vB.w * aB) / lt;
        int dbase = h * 260 + l * 4;
        hEnS[(dbase + 0) * 4 + fbb] = v.x; hEnS[(dbase + 1) * 4 + fbb] = v.y;
        hEnS[(dbase + 2) * 4 + fbb] = v.z; hEnS[(dbase + 3) * 4 + fbb] = v.w;
      }
    }
    __syncthreads();

    // ================= POST =================
    // heads = hEn @ Wv strips   (K=256 din, slice 32/wave)
    {
      const int h = l >> 3;
      float4 a0 = f4z(), a1 = f4z(), a2 = f4z(), a3 = f4z();
      const float* wp = Wv + (size_t)(ks * 32) * DD + c0;
#pragma unroll 8
      for (int k = 0; k < 32; ++k) {
        float4 wv = *(const float4*)wp; wp += DD;
        float4 hv = *(float4*)&hEnS[(h * 260 + ks * 32 + k) * 4];
        a0 = svfma(hv.x, wv, a0); a1 = svfma(hv.y, wv, a1);
        a2 = svfma(hv.z, wv, a2); a3 = svfma(hv.w, wv, a3);
      }
      *(float4*)&qkS[ks * 1024 + 0 * 256 + c0] = a0;
      *(float4*)&qkS[ks * 1024 + 1 * 256 + c0] = a1;
      *(float4*)&qkS[ks * 1024 + 2 * 256 + c0] = a2;
      *(float4*)&qkS[ks * 1024 + 3 * 256 + c0] = a3;
    }
    __syncthreads();
    {  // heads combine
      int bb = t & 3, cb = t >> 2;
#pragma unroll
      for (int it = 0; it < 2; ++it) {
        int c = cb + it * 128;
        float s = 0.f;
#pragma unroll
        for (int sl = 0; sl < 8; ++sl) s += qkS[sl * 1024 + bb * 256 + c];
        headsS[c * 4 + bb] = s;
      }
    }
    __syncthreads();

    // qlin' = heads @ M1 ; gl2 = heads @ M2  (fused, parts->qkS/hEnS)
    {
      float4 x0 = f4z(), x1 = f4z(), x2 = f4z(), x3 = f4z();
      float4 y0 = f4z(), y1 = f4z(), y2 = f4z(), y3 = f4z();
      const float* p1 = M1 + (size_t)(ks * 32) * DD + c0;
      const float* p2 = M2 + (size_t)(ks * 32) * DD + c0;
      const float* hp = headsS + (ks * 32) * 4;
#pragma unroll 4
      for (int k = 0; k < 32; ++k) {
        float4 w1v = *(const float4*)p1; p1 += DD;
        float4 w2v = *(const float4*)p2; p2 += DD;
        float4 hv = *(const float4*)hp; hp += 4;
        x0 = svfma(hv.x, w1v, x0); x1 = svfma(hv.y, w1v, x1);
        x2 = svfma(hv.z, w1v, x2); x3 = svfma(hv.w, w1v, x3);
        y0 = svfma(hv.x, w2v, y0); y1 = svfma(hv.y, w2v, y1);
        y2 = svfma(hv.z, w2v, y2); y3 = svfma(hv.w, w2v, y3);
      }
      *(float4*)&qkS[ks * 1024 + 0 * 256 + c0] = x0;
      *(float4*)&qkS[ks * 1024 + 1 * 256 + c0] = x1;
      *(float4*)&qkS[ks * 1024 + 2 * 256 + c0] = x2;
      *(float4*)&qkS[ks * 1024 + 3 * 256 + c0] = x3;
      *(float4*)&hEnS[ks * 1024 + 0 * 256 + c0] = y0;
      *(float4*)&hEnS[ks * 1024 + 1 * 256 + c0] = y1;
      *(float4*)&hEnS[ks * 1024 + 2 * 256 + c0] = y2;
      *(float4*)&hEnS[ks * 1024 + 3 * 256 + c0] = y3;
    }
    __syncthreads();
    {  // M combine
      int bb = t & 3, cb = t >> 2;
#pragma unroll
      for (int it = 0; it < 2; ++it) {
        int c = cb + it * 128;
        float s1 = 0.f, s2 = 0.f;
#pragma unroll
        for (int sl = 0; sl < 8; ++sl) {
          s1 += qkS[sl * 1024 + bb * 256 + c];
          s2 += hEnS[sl * 1024 + bb * 256 + c];
        }
        qlinS[bb][c] = s1;
        gl2S[bb][c] = s2;
      }
    }
    __syncthreads();

    // ================= SELECT =================
    {
      int sbb = t >> 7, rid = (t & 127) >> 3, seg = t & 7;
      const float* Es = E + (size_t)(blk * 4 + sbb) * (NN * DD);
      const float* gp = &gl2S[sbb][seg * 32];
      int chunks = (cnt + 15) >> 4;
      for (int ch = 0; ch < chunks; ++ch) {
        int idx = ch * 16 + rid;
        bool val = idx < cnt;
        int row = lstS[sbb][val ? idx : 0];
        const float* ep = Es + row * DD + seg * 32;
        float4 acc = f4z();
#pragma unroll
        for (int j = 0; j < 8; ++j)
          acc = f4fma(*(const float4*)(ep + j * 4),
                      *(const float4*)(gp + j * 4), acc);
        float s = (acc.x + acc.y) + (acc.z + acc.w);
        s += __shfl_xor(s, 1);
        s += __shfl_xor(s, 2);
        s += __shfl_xor(s, 4);
        if (val && seg == 0) logitS[sbb][idx] = 10.f * tanhf(s * 0.0625f);
      }
    }
    __syncthreads();
    if (w2 == 0) {  // one wave per b: argmax + sumexp trees (round-1 order)
      float v0 = (l < cnt) ? logitS[fbb][l] : -INFINITY;
      float v1 = (l + 64 < cnt) ? logitS[fbb][l + 64] : -INFINITY;
      float bv; int bi;
      if (v1 > v0) { bv = v1; bi = l + 64; } else { bv = v0; bi = l; }
#pragma unroll
      for (int off = 32; off >= 1; off >>= 1) {
        float ov = __shfl_xor(bv, off);
        int oi = __shfl_xor(bi, off);
        if (ov > bv || (ov == bv && oi < bi)) { bv = ov; bi = oi; }
      }
      float p0 = (l < cnt) ? expf(v0 - bv) : 0.f;
      float p1 = (l + 64 < cnt) ? expf(v1 - bv) : 0.f;
      float s = p0 + p1;
#pragma unroll
      for (int off = 32; off >= 1; off >>= 1) s += __shfl_xor(s, off);
      if (l == 0) {
        int sel = lstS[fbb][bi];
        float logp = -logf(s);
        visS[fbb][sel >> 5] |= (1u << (sel & 31));
        int gb = blk * 4 + fbb;
        float cx = coords[(size_t)gb * 256 + sel * 2];
        float cy = coords[(size_t)gb * 256 + sel * 2 + 1];
        stS[fbb][0] += logp;
        if (step == 0) {
          fpS[fbb][0] = sel; stS[fbb][2] = cx; stS[fbb][3] = cy;
        } else {
          float dx = stS[fbb][4] - cx, dy = stS[fbb][5] - cy;
          stS[fbb][1] += sqrtf(dx * dx + dy * dy);
        }
        fpS[fbb][1] = sel; stS[fbb][4] = cx; stS[fbb][5] = cy;
        if (step == NN - 1) {
          float dx = cx - stS[fbb][2], dy = cy - stS[fbb][3];
          out[gb] = stS[fbb][1] + sqrtf(dx * dx + dy * dy);
          out[BB + gb] = stS[fbb][0];
        }
      }
    }
    __syncthreads();
  }
}

// ---------------------------------------------------------------------------
extern "C" void kernel_launch(void* const* d_in, const int* in_sizes, int n_in,
                              void* d_out, int out_size, void* d_ws, size_t ws_size,
                              hipStream_t stream) {
  const float* coords = (const float*)d_in[0];
  const float* E      = (const float*)d_in[1];
  const float* Wk     = (const float*)d_in[2];
  const float* Wv     = (const float*)d_in[3];
  const float* Wlk    = (const float*)d_in[4];
  const float* Wo     = (const float*)d_in[5];
  const float* Wc     = (const float*)d_in[6];
  const float* Ws     = (const float*)d_in[7];
  const float* Wph    = (const float*)d_in[8];
  const float* W1     = (const float*)d_in[9];
  const float* b1     = (const float*)d_in[10];
  const float* W2     = (const float*)d_in[11];
  const float* b2     = (const float*)d_in[12];
  float* out = (float*)d_out;

  float* w = (float*)d_ws;
  float* g0    = w;                        // 1024*256
  float* qlin0 = g0 + (size_t)BB * DD;     // 1024*256
  float* WkT   = qlin0 + (size_t)BB * DD;  // 256*256
  float* M1    = WkT + DD * DD;            // 256*256
  float* M2    = M1 + DD * DD;             // 256*256

  k_mean<<<BB, 256, 0, stream>>>(E, g0);
  k_transpose<<<64, 256, 0, stream>>>(Wk, WkT);
  k_gemm<<<dim3(8, 8), 256, 0, stream>>>(Wo, Wc, M1, 256, 256, 256, 0);
  k_gemm<<<dim3(8, 8), 256, 0, stream>>>(Wo, Wlk, M2, 256, 256, 256, 1);
  k_gemm<<<dim3(8, 32), 256, 0, stream>>>(g0, Wc, qlin0, 1024, 256, 256, 0);
  k_decode<<<256, 512, 0, stream>>>(E, coords, Ws, W1, b1, W2, b2, WkT, Wv,
                                    M1, M2, Wph, qlin0, out);
}